// Round 10
// baseline (325.373 us; speedup 1.0000x reference)
//
#include <hip/hip_runtime.h>
#include <hip/hip_bf16.h>

#define N_NODES 50000
#define N_PAD 50176        // padded to 3136 row-tiles of 16
#define N_EDGES 500000
#define E2_EDGES 550000    // with self loops appended
#define F_IN 32
#define HEADS 4
#define CH 64
#define HC 256             // HEADS*CH
#define NB 1000
#define NHID 256
#define NOUT 256
#define SLOT_CAP 64        // bucket capacity; deg ~ Poisson(10)+1, P(>63) ~ 0

static inline int cdiv(long long a, long long b) { return (int)((a + b - 1) / b); }

typedef __bf16 bf16x8 __attribute__((ext_vector_type(8)));
typedef unsigned short us8 __attribute__((ext_vector_type(8)));
typedef float f32x4 __attribute__((ext_vector_type(4)));
union BU { us8 u; bf16x8 b; };

// round-to-nearest-even fp32 -> bf16 (bit pattern)
__device__ inline unsigned short f2bf(float f) {
    unsigned u = __float_as_uint(f);
    return (unsigned short)((u + 0x7fffu + ((u >> 16) & 1u)) >> 16);
}
__device__ inline float bf2f(unsigned short h) {
    return __uint_as_float(((unsigned)h) << 16);
}

// ---------- device helpers for fused prep ----------
__device__ inline void wconv_one(const float* __restrict__ W,
                                 unsigned short* __restrict__ Wf_hi,
                                 unsigned short* __restrict__ Wf_lo,
                                 int K, int M, int idx) {
    int k = idx / M, m = idx % M;
    float v = W[idx];
    unsigned short hi = f2bf(v);
    unsigned short lo = f2bf(v - bf2f(hi));
    int tcol = m >> 4, l16 = m & 15;
    int ch = k >> 5, quad = (k >> 3) & 3, j = k & 7;
    int NCH = K >> 5;
    size_t dst = ((((size_t)tcol * NCH + ch) * 64) + quad * 16 + l16) * 8 + j;
    Wf_hi[dst] = hi;
    Wf_lo[dst] = lo;
}

// ---------- fused prep: deg zero + x split (A-frag) + 3x W conv ----------
#define PREP_T0 N_NODES
#define PREP_T1 (PREP_T0 + N_NODES * F_IN)
#define PREP_T2 (PREP_T1 + F_IN * HC)
#define PREP_T3 (PREP_T2 + HC * HC)
#define PREP_T4 (PREP_T3 + HC * CH)
__global__ void prep_kernel(const float* __restrict__ x,
                            unsigned short* __restrict__ xh,
                            unsigned short* __restrict__ xl,
                            const float* __restrict__ W1,
                            unsigned short* __restrict__ wt1h, unsigned short* __restrict__ wt1l,
                            const float* __restrict__ W2,
                            unsigned short* __restrict__ wt2h, unsigned short* __restrict__ wt2l,
                            const float* __restrict__ W3,
                            unsigned short* __restrict__ wt3h, unsigned short* __restrict__ wt3l,
                            int* __restrict__ deg) {
    int t = blockIdx.x * blockDim.x + threadIdx.x;
    if (t < PREP_T0) {
        deg[t] = 0;
    } else if (t < PREP_T1) {
        int i = t - PREP_T0;
        int node = i / F_IN, c = i % F_IN;
        float v = x[i];
        unsigned short hi = f2bf(v);
        size_t dst = (((size_t)(node >> 4)) * 64 + ((c >> 3) & 3) * 16 + (node & 15)) * 8 + (c & 7);
        xh[dst] = hi;
        xl[dst] = f2bf(v - bf2f(hi));
    } else if (t < PREP_T2) {
        wconv_one(W1, wt1h, wt1l, F_IN, HC, t - PREP_T1);
    } else if (t < PREP_T3) {
        wconv_one(W2, wt2h, wt2l, HC, HC, t - PREP_T2);
    } else if (t < PREP_T4) {
        wconv_one(W3, wt3h, wt3l, HC, CH, t - PREP_T3);
    }
}

// ================== device phase bodies ==================

// single-pass bucketed CSR scatter: one 256-edge tile (deg zeroed by prep)
__device__ __forceinline__ void scatter_tile(int t, const int* __restrict__ ei,
                                             int* __restrict__ deg,
                                             unsigned short* __restrict__ slots) {
    int e = t * 256 + threadIdx.x;
    if (e >= E2_EDGES) return;
    int s, d;
    if (e < N_EDGES) { s = ei[e]; d = ei[N_EDGES + e]; }
    else             { s = d = e - N_EDGES; }
    int pos = atomicAdd(deg + d, 1);
    if (pos < SLOT_CAP) slots[(d << 6) + pos] = (unsigned short)s;
}

// fused split-bf16 MFMA GEMM + attention logits, one 64(or 256)-row tile
template<int K, int M, bool ALO>
__device__ __forceinline__ void gemm_tile(
    int bid,
    const unsigned short* __restrict__ Ah, const unsigned short* __restrict__ Al,
    const unsigned short* __restrict__ Wf_hi, const unsigned short* __restrict__ Wf_lo,
    const float* __restrict__ a_src, const float* __restrict__ a_dst,
    unsigned short* __restrict__ Hout, float* __restrict__ als,
    float* __restrict__ ald, int n_rows) {
    constexpr int NCH = K / 32;
    constexpr int CW = M / 64;
    constexpr int RW = 4 / CW;
    constexpr int H_ = M / 64;
    const int wave = threadIdx.x >> 6, lane = threadIdx.x & 63;
    const int quad = lane >> 4, l16 = lane & 15;
    const int head = wave % CW;
    const int col0 = head * 64;
    const int row0 = bid * (RW * 64) + (wave / CW) * 64;
    const int rt0 = row0 >> 4;

    f32x4 acc[4][4];
#pragma unroll
    for (int rs = 0; rs < 4; rs++)
#pragma unroll
        for (int t = 0; t < 4; t++) acc[rs][t] = (f32x4){0.f, 0.f, 0.f, 0.f};

    const unsigned short* aph[4];
    const unsigned short* apl[4];
#pragma unroll
    for (int rs = 0; rs < 4; rs++) {
        size_t off = (((size_t)(rt0 + rs) * NCH) * 64 + lane) * 8;
        aph[rs] = Ah + off;
        if (ALO) apl[rs] = Al + off;
    }
    const unsigned short* bh = Wf_hi + ((size_t)(col0 >> 4) * NCH * 64 + lane) * 8;
    const unsigned short* bl = Wf_lo + ((size_t)(col0 >> 4) * NCH * 64 + lane) * 8;

#pragma unroll
    for (int ch = 0; ch < NCH; ch++) {
        BU a_h[4], a_l[4], b_h[4], b_l[4];
#pragma unroll
        for (int rs = 0; rs < 4; rs++) {
            a_h[rs].u = *(const us8*)(aph[rs] + ch * 512);
            if (ALO) a_l[rs].u = *(const us8*)(apl[rs] + ch * 512);
        }
#pragma unroll
        for (int t = 0; t < 4; t++) {
            b_h[t].u = *(const us8*)(bh + (size_t)(t * NCH + ch) * 512);
            b_l[t].u = *(const us8*)(bl + (size_t)(t * NCH + ch) * 512);
        }
#pragma unroll
        for (int t = 0; t < 4; t++) {
#pragma unroll
            for (int rs = 0; rs < 4; rs++) {
                acc[rs][t] = __builtin_amdgcn_mfma_f32_16x16x32_bf16(a_h[rs].b, b_h[t].b, acc[rs][t], 0, 0, 0);
                acc[rs][t] = __builtin_amdgcn_mfma_f32_16x16x32_bf16(a_h[rs].b, b_l[t].b, acc[rs][t], 0, 0, 0);
                if (ALO)
                    acc[rs][t] = __builtin_amdgcn_mfma_f32_16x16x32_bf16(a_l[rs].b, b_h[t].b, acc[rs][t], 0, 0, 0);
            }
        }
    }

    float sv[4], dv[4];
#pragma unroll
    for (int t = 0; t < 4; t++) {
        sv[t] = a_src[col0 + t * 16 + l16];
        dv[t] = a_dst[col0 + t * 16 + l16];
    }
#pragma unroll
    for (int rs = 0; rs < 4; rs++) {
        const int orow0 = row0 + rs * 16 + quad * 4;
#pragma unroll
        for (int i = 0; i < 4; i++) {
            int r = orow0 + i;
            bool ok = (r < n_rows);
            float ps = 0.f, pd = 0.f;
#pragma unroll
            for (int t = 0; t < 4; t++) {
                float v = acc[rs][t][i];
                ps += v * sv[t];
                pd += v * dv[t];
                if (ok) Hout[(size_t)r * M + col0 + t * 16 + l16] = f2bf(v);
            }
            ps += __shfl_xor(ps, 1);  pd += __shfl_xor(pd, 1);
            ps += __shfl_xor(ps, 2);  pd += __shfl_xor(pd, 2);
            ps += __shfl_xor(ps, 4);  pd += __shfl_xor(pd, 4);
            ps += __shfl_xor(ps, 8);  pd += __shfl_xor(pd, 8);
            if (l16 == 0 && ok) {
                als[r * H_ + head] = ps;
                ald[r * H_ + head] = pd;
            }
        }
    }
}

#define NT_G1 ((N_NODES + 63) / 64)      // 782 gemm1 tiles
#define NT_SC ((E2_EDGES + 255) / 256)   // 2149 scatter tiles

// ===== merged layer-1 GEMM + CSR scatter (independent work, one launch): ====
// removes one kernel boundary and hides scatter's ~7us under the GEMM.
__global__ __launch_bounds__(256) void gemm1_scatter_kernel(
    const unsigned short* __restrict__ Ah, const unsigned short* __restrict__ Al,
    const unsigned short* __restrict__ Wf_hi, const unsigned short* __restrict__ Wf_lo,
    const float* __restrict__ a_src, const float* __restrict__ a_dst,
    unsigned short* __restrict__ Hout, float* __restrict__ als,
    float* __restrict__ ald,
    const int* __restrict__ ei, int* __restrict__ deg,
    unsigned short* __restrict__ slots) {
    if (blockIdx.x < NT_G1)
        gemm_tile<F_IN, HC, true>(blockIdx.x, Ah, Al, Wf_hi, Wf_lo, a_src, a_dst,
                                  Hout, als, ald, N_NODES);
    else
        scatter_tile(blockIdx.x - NT_G1, ei, deg, slots);
}

template<int K, int M, bool ALO>
__global__ __launch_bounds__(256) void mfma_lin_fused_kernel(
    const unsigned short* __restrict__ Ah, const unsigned short* __restrict__ Al,
    const unsigned short* __restrict__ Wf_hi, const unsigned short* __restrict__ Wf_lo,
    const float* __restrict__ a_src, const float* __restrict__ a_dst,
    unsigned short* __restrict__ Hout, float* __restrict__ als,
    float* __restrict__ ald, int n_rows) {
    gemm_tile<K, M, ALO>(blockIdx.x, Ah, Al, Wf_hi, Wf_lo, a_src, a_dst, Hout, als, ald, n_rows);
}

// ===== agg (layers 1,2): bucketed ushort slots, v8 batch structure =====
// (at its ~3.3 TB/s / ~88K-lines-per-us gather ceiling; v5/v7/v8 all ~50us)
__global__ __launch_bounds__(256, 4) void gat_agg_v3_kernel(
    const unsigned short* __restrict__ slots, const int* __restrict__ deg,
    const unsigned short* __restrict__ h,
    const float* __restrict__ als, const float* __restrict__ ald,
    const float* __restrict__ bias, unsigned short* __restrict__ outh) {
    constexpr int LP = 264;            // LDS row stride (shorts), 16B-aligned
    __shared__ unsigned short smh[16 * LP];
    const int tid = threadIdx.x;
    const int wave = tid >> 6, lane = tid & 63;
    const int cl = lane & 31, half = lane >> 5;
    const int head = cl >> 3;          // 8 lanes per head (8 ch each)
    const int rt = blockIdx.x;         // row tile: nodes rt*16 .. rt*16+15

    float bv[8];
#pragma unroll
    for (int i = 0; i < 8; i++) bv[i] = bias[cl * 8 + i];

    const int nb = rt * 16 + wave * 4;
    int lenv[4];
    float adv[4];
#pragma unroll
    for (int nn = 0; nn < 4; nn++) {
        lenv[nn] = min(deg[nb + nn], SLOT_CAP);
        adv[nn] = ald[((nb + nn) << 2) + head];
    }
    const unsigned short* hp = h + cl * 8;

    for (int nn = 0; nn < 4; nn++) {
        const int len = lenv[nn];
        const int lm = len - 1;          // len >= 1 (self loop)
        const int base = (nb + nn) << 6; // slot base
        const float ad = adv[nn];
        float z = 0.f;
        float a[8];
#pragma unroll
        for (int i = 0; i < 8; i++) a[i] = 0.f;
        for (int k = 0; k < len; k += 16) {
            int ss[8];
#pragma unroll
            for (int j = 0; j < 8; j++) {
                int ii = min(k + 2 * j + half, lm);
                ss[j] = (int)slots[base + ii];
            }
            __builtin_amdgcn_sched_barrier(0);
            us8 hv[8];
            float alv[8];
#pragma unroll
            for (int j = 0; j < 8; j++) {
                hv[j] = *(const us8*)(hp + ((size_t)ss[j] << 8));
                alv[j] = als[(ss[j] << 2) + head];
            }
            __builtin_amdgcn_sched_barrier(0);
            float p[8];
#pragma unroll
            for (int j = 0; j < 8; j++) {
                float x = alv[j] + ad;
                x = (x > 0.f) ? x : 0.2f * x;
                int e = k + 2 * j + half;
                p[j] = (e < len) ? __expf(x) : 0.f;
                z += p[j];
            }
#pragma unroll
            for (int j = 0; j < 8; j++)
#pragma unroll
                for (int i = 0; i < 8; i++)
                    a[i] += p[j] * bf2f(hv[j][i]);
        }
        z += __shfl_xor(z, 32);
#pragma unroll
        for (int i = 0; i < 8; i++) a[i] += __shfl_xor(a[i], 32);
        if (half == 0) {
            float inv = 1.f / (z + 1e-16f);
            us8 vh;
#pragma unroll
            for (int i = 0; i < 8; i++) {
                float v = fmaxf(a[i] * inv + bv[i], 0.f);   // relu (layers 1,2)
                vh[i] = f2bf(v);
            }
            int nl = wave * 4 + nn;
            *(us8*)(smh + nl * LP + cl * 8) = vh;
        }
    }
    __syncthreads();
#pragma unroll
    for (int f = tid; f < 512; f += 256) {
        int chunk = f >> 6, ln2 = f & 63;
        int quad = ln2 >> 4, l16 = ln2 & 15;
        us8 vh = *(const us8*)(smh + l16 * LP + chunk * 32 + quad * 8);
        size_t dst = (((size_t)rt * 8 + chunk) * 64 + ln2) * 8;
        *(us8*)(outh + dst) = vh;
    }
}

// ===== fused layer-3 agg + head: one block per graph. The block's 4 waves
// aggregate the graph's nodes (exact agg_h1 inner loop; the shfl_xor
// butterfly leaves EVERY lane holding the full per-channel sum, so per-wave
// register accumulation across nodes is free), partials -> LDS, then the
// same block runs mean -> MLP1 -> MLP2 -> LayerNorm. Deletes the 25.6MB
// bufO3 round-trip and one kernel boundary. xg = sum(alpha.h)/cnt + b3
// (bias once after the mean -- algebraically identical to per-node bias).
__global__ __launch_bounds__(256) void agg3_head_kernel(
    const unsigned short* __restrict__ slots, const int* __restrict__ deg,
    const unsigned short* __restrict__ h,
    const float* __restrict__ als, const float* __restrict__ ald,
    const float* __restrict__ b3, const int* __restrict__ batch,
    const float* __restrict__ Wm1, const float* __restrict__ bm1,
    const float* __restrict__ Wm2, const float* __restrict__ bm2,
    const float* __restrict__ g2, const float* __restrict__ be2,
    float* __restrict__ out) {
    const int b = blockIdx.x;
    const int tid = threadIdx.x;
    const int wave = tid >> 6, lane = tid & 63;
    const int eg = lane >> 3, cg = lane & 7;   // edge slot, channel group

    // node range of graph b (batch is sorted)
    int lo = 0, hi = N_NODES;
    while (lo < hi) { int mid = (lo + hi) >> 1; if (batch[mid] < b) lo = mid + 1; else hi = mid; }
    const int start = lo;
    hi = N_NODES;
    while (lo < hi) { int mid = (lo + hi) >> 1; if (batch[mid] < b + 1) lo = mid + 1; else hi = mid; }
    const int end = lo;
    const int cnt = end - start;

    __shared__ float wsum[4][CH];
    __shared__ float xg[CH];
    __shared__ float yr[NHID];
    __shared__ float red[8];
    __shared__ float mv[2];
    wsum[wave][lane & 63] = 0.f;   // each wave zeroes its own row (64 lanes)

    float asum[8];
#pragma unroll
    for (int i = 0; i < 8; i++) asum[i] = 0.f;
    const unsigned short* hp = h + cg * 8;

    // wave-strided nodes of this graph (agg_h1 inner loop per node)
    for (int node = start + wave; node < end; node += 4) {
        const int base = node << 6;
        const int len = min(deg[node], SLOT_CAP);
        const float ad = ald[node];
        float z = 0.f;
        float a[8];
#pragma unroll
        for (int i = 0; i < 8; i++) a[i] = 0.f;
        for (int k = 0; k < len; k += 8) {
            int e = k + eg;
            int s0 = (int)slots[base + min(e, len - 1)];
            us8 hv = *(const us8*)(hp + ((size_t)s0 << 6));
            float x = als[s0] + ad;
            x = (x > 0.f) ? x : 0.2f * x;
            float p = (e < len) ? __expf(x) : 0.f;
            z += p;
#pragma unroll
            for (int i = 0; i < 8; i++) a[i] += p * bf2f(hv[i]);
        }
#pragma unroll
        for (int off = 8; off <= 32; off <<= 1) {
            z += __shfl_xor(z, off);
#pragma unroll
            for (int i = 0; i < 8; i++) a[i] += __shfl_xor(a[i], off);
        }
        float inv = 1.f / (z + 1e-16f);
#pragma unroll
        for (int i = 0; i < 8; i++) asum[i] += a[i] * inv;
    }
    if (eg == 0) {
#pragma unroll
        for (int i = 0; i < 8; i++) wsum[wave][cg * 8 + i] = asum[i];
    }
    __syncthreads();
    if (tid < CH) {
        float t = wsum[0][tid] + wsum[1][tid] + wsum[2][tid] + wsum[3][tid];
        xg[tid] = t / fmaxf((float)cnt, 1.f) + b3[tid];
    }
    __syncthreads();
    // MLP1: y1 = relu(xg @ Wm1 + bm1)
    float acc1 = bm1[tid];
#pragma unroll 8
    for (int k = 0; k < CH; k++) acc1 += xg[k] * Wm1[(size_t)k * NHID + tid];
    yr[tid] = fmaxf(acc1, 0.f);
    __syncthreads();
    // MLP2: y2 = y1 @ Wm2 + bm2
    float acc = bm2[tid];
#pragma unroll 8
    for (int k = 0; k < NHID; k++) acc += yr[k] * Wm2[(size_t)k * NOUT + tid];
    // LayerNorm over 256
    float ss = acc, s2 = acc * acc;
    for (int o = 32; o > 0; o >>= 1) {
        ss += __shfl_down(ss, o);
        s2 += __shfl_down(s2, o);
    }
    if ((tid & 63) == 0) { red[wave] = ss; red[4 + wave] = s2; }
    __syncthreads();
    if (tid == 0) {
        float ts = red[0] + red[1] + red[2] + red[3];
        float ts2 = red[4] + red[5] + red[6] + red[7];
        float mu = ts / (float)NOUT;
        float var = ts2 / (float)NOUT - mu * mu;
        mv[0] = mu;
        mv[1] = rsqrtf(var + 1e-5f);
    }
    __syncthreads();
    out[(size_t)b * NOUT + tid] = (acc - mv[0]) * mv[1] * g2[tid] + be2[tid];
}

extern "C" void kernel_launch(void* const* d_in, const int* in_sizes, int n_in,
                              void* d_out, int out_size, void* d_ws, size_t ws_size,
                              hipStream_t stream) {
    const float* x      = (const float*)d_in[0];
    const int*   ei     = (const int*)d_in[1];
    const int*   batch  = (const int*)d_in[2];
    const float* W1     = (const float*)d_in[3];
    const float* as1    = (const float*)d_in[4];
    const float* ad1    = (const float*)d_in[5];
    const float* b1     = (const float*)d_in[6];
    const float* W2     = (const float*)d_in[7];
    const float* as2    = (const float*)d_in[8];
    const float* ad2    = (const float*)d_in[9];
    const float* b2     = (const float*)d_in[10];
    const float* W3     = (const float*)d_in[11];
    const float* as3    = (const float*)d_in[12];
    const float* ad3    = (const float*)d_in[13];
    const float* b3     = (const float*)d_in[14];
    const float* Wm1    = (const float*)d_in[15];
    const float* bm1    = (const float*)d_in[16];
    const float* Wm2    = (const float*)d_in[17];
    const float* bm2    = (const float*)d_in[18];
    const float* g2     = (const float*)d_in[19];
    const float* be2    = (const float*)d_in[20];
    float* out = (float*)d_out;

    // workspace layout (~66.5MB, below the proven footprint)
    unsigned short* bufH = (unsigned short*)d_ws;                  // N*HC bf16
    unsigned short* aggh = bufH + (size_t)N_NODES * HC;            // N_PAD*HC frag-major
    unsigned short* xh   = aggh + (size_t)N_PAD * HC;              // N_PAD*F_IN
    unsigned short* xl   = xh + (size_t)N_PAD * F_IN;              // N_PAD*F_IN
    unsigned short* slots = xl + (size_t)N_PAD * F_IN;             // N*SLOT_CAP (dedicated)
    float* als   = (float*)(slots + (size_t)N_NODES * SLOT_CAP);   // N*HEADS
    float* ald   = als + (size_t)N_NODES * HEADS;                  // N*HEADS
    int* deg     = (int*)(ald + (size_t)N_NODES * HEADS);          // N
    unsigned short* wt1h = (unsigned short*)(deg + N_NODES);       // 256*32
    unsigned short* wt1l = wt1h + 256 * 32;
    unsigned short* wt2h = wt1l + 256 * 32;                        // 256*256
    unsigned short* wt2l = wt2h + 256 * 256;
    unsigned short* wt3h = wt2l + 256 * 256;                       // 64*256
    unsigned short* wt3l = wt3h + 64 * 256;

    const int BLK = 256;

    // ===================== fused prep (deg zero, x split, W conv) ============
    prep_kernel<<<cdiv(PREP_T4, BLK), BLK, 0, stream>>>(
        x, xh, xl, W1, wt1h, wt1l, W2, wt2h, wt2l, W3, wt3h, wt3l, deg);

    // ===================== Layer-1 GEMM + CSR scatter (merged launch) ========
    gemm1_scatter_kernel<<<NT_G1 + NT_SC, 256, 0, stream>>>(
        xh, xl, wt1h, wt1l, as1, ad1, bufH, als, ald, ei, deg, slots);

    // ===================== Layer 1 aggregation =====================
    gat_agg_v3_kernel<<<N_NODES / 16, 256, 0, stream>>>(
        slots, deg, bufH, als, ald, b1, aggh);

    // ===================== Layer 2 (H*C -> H*C) =====================
    mfma_lin_fused_kernel<HC, HC, false><<<cdiv(N_NODES, 64), 256, 0, stream>>>(
        aggh, nullptr, wt2h, wt2l, as2, ad2, bufH, als, ald, N_NODES);
    gat_agg_v3_kernel<<<N_NODES / 16, 256, 0, stream>>>(
        slots, deg, bufH, als, ald, b2, aggh);

    // ===================== Layer 3 GEMM (H*C -> C, heads=1) ==================
    mfma_lin_fused_kernel<HC, CH, false><<<cdiv(N_NODES, 256), 256, 0, stream>>>(
        aggh, nullptr, wt3h, wt3l, as3, ad3, bufH, als, ald, N_NODES);

    // ===================== fused layer-3 agg + pool + MLP + LayerNorm ========
    agg3_head_kernel<<<NB, 256, 0, stream>>>(
        slots, deg, bufH, als, ald, b3, batch, Wm1, bm1, Wm2, bm2, g2, be2, out);
}

// Round 11
// 317.996 us; speedup vs baseline: 1.0232x; 1.0232x over previous
//
#include <hip/hip_runtime.h>
#include <hip/hip_bf16.h>

#define N_NODES 50000
#define N_PAD 50176        // padded to 3136 row-tiles of 16
#define N_EDGES 500000
#define E2_EDGES 550000    // with self loops appended
#define F_IN 32
#define HEADS 4
#define CH 64
#define HC 256             // HEADS*CH
#define NB 1000
#define NHID 256
#define NOUT 256
#define SLOT_CAP 64        // bucket capacity; deg ~ Poisson(10)+1, P(>63) ~ 0

static inline int cdiv(long long a, long long b) { return (int)((a + b - 1) / b); }

typedef __bf16 bf16x8 __attribute__((ext_vector_type(8)));
typedef unsigned short us8 __attribute__((ext_vector_type(8)));
typedef float f32x4 __attribute__((ext_vector_type(4)));
union BU { us8 u; bf16x8 b; };

// round-to-nearest-even fp32 -> bf16 (bit pattern)
__device__ inline unsigned short f2bf(float f) {
    unsigned u = __float_as_uint(f);
    return (unsigned short)((u + 0x7fffu + ((u >> 16) & 1u)) >> 16);
}
__device__ inline float bf2f(unsigned short h) {
    return __uint_as_float(((unsigned)h) << 16);
}

// ---------- device helpers for fused prep ----------
__device__ inline void wconv_one(const float* __restrict__ W,
                                 unsigned short* __restrict__ Wf_hi,
                                 unsigned short* __restrict__ Wf_lo,
                                 int K, int M, int idx) {
    int k = idx / M, m = idx % M;
    float v = W[idx];
    unsigned short hi = f2bf(v);
    unsigned short lo = f2bf(v - bf2f(hi));
    int tcol = m >> 4, l16 = m & 15;
    int ch = k >> 5, quad = (k >> 3) & 3, j = k & 7;
    int NCH = K >> 5;
    size_t dst = ((((size_t)tcol * NCH + ch) * 64) + quad * 16 + l16) * 8 + j;
    Wf_hi[dst] = hi;
    Wf_lo[dst] = lo;
}

// ---------- fused prep: deg zero + x split (A-frag) + 3x W conv ----------
#define PREP_T0 N_NODES
#define PREP_T1 (PREP_T0 + N_NODES * F_IN)
#define PREP_T2 (PREP_T1 + F_IN * HC)
#define PREP_T3 (PREP_T2 + HC * HC)
#define PREP_T4 (PREP_T3 + HC * CH)
__global__ void prep_kernel(const float* __restrict__ x,
                            unsigned short* __restrict__ xh,
                            unsigned short* __restrict__ xl,
                            const float* __restrict__ W1,
                            unsigned short* __restrict__ wt1h, unsigned short* __restrict__ wt1l,
                            const float* __restrict__ W2,
                            unsigned short* __restrict__ wt2h, unsigned short* __restrict__ wt2l,
                            const float* __restrict__ W3,
                            unsigned short* __restrict__ wt3h, unsigned short* __restrict__ wt3l,
                            int* __restrict__ deg) {
    int t = blockIdx.x * blockDim.x + threadIdx.x;
    if (t < PREP_T0) {
        deg[t] = 0;
    } else if (t < PREP_T1) {
        int i = t - PREP_T0;
        int node = i / F_IN, c = i % F_IN;
        float v = x[i];
        unsigned short hi = f2bf(v);
        size_t dst = (((size_t)(node >> 4)) * 64 + ((c >> 3) & 3) * 16 + (node & 15)) * 8 + (c & 7);
        xh[dst] = hi;
        xl[dst] = f2bf(v - bf2f(hi));
    } else if (t < PREP_T2) {
        wconv_one(W1, wt1h, wt1l, F_IN, HC, t - PREP_T1);
    } else if (t < PREP_T3) {
        wconv_one(W2, wt2h, wt2l, HC, HC, t - PREP_T2);
    } else if (t < PREP_T4) {
        wconv_one(W3, wt3h, wt3l, HC, CH, t - PREP_T3);
    }
}

// ================== device phase bodies ==================

// single-pass bucketed CSR scatter: one 256-edge tile (deg zeroed by prep)
__device__ __forceinline__ void scatter_tile(int t, const int* __restrict__ ei,
                                             int* __restrict__ deg,
                                             unsigned short* __restrict__ slots) {
    int e = t * 256 + threadIdx.x;
    if (e >= E2_EDGES) return;
    int s, d;
    if (e < N_EDGES) { s = ei[e]; d = ei[N_EDGES + e]; }
    else             { s = d = e - N_EDGES; }
    int pos = atomicAdd(deg + d, 1);
    if (pos < SLOT_CAP) slots[(d << 6) + pos] = (unsigned short)s;
}

// fused split-bf16 MFMA GEMM + attention logits, one 64(or 256)-row tile
template<int K, int M, bool ALO>
__device__ __forceinline__ void gemm_tile(
    int bid,
    const unsigned short* __restrict__ Ah, const unsigned short* __restrict__ Al,
    const unsigned short* __restrict__ Wf_hi, const unsigned short* __restrict__ Wf_lo,
    const float* __restrict__ a_src, const float* __restrict__ a_dst,
    unsigned short* __restrict__ Hout, float* __restrict__ als,
    float* __restrict__ ald, int n_rows) {
    constexpr int NCH = K / 32;
    constexpr int CW = M / 64;
    constexpr int RW = 4 / CW;
    constexpr int H_ = M / 64;
    const int wave = threadIdx.x >> 6, lane = threadIdx.x & 63;
    const int quad = lane >> 4, l16 = lane & 15;
    const int head = wave % CW;
    const int col0 = head * 64;
    const int row0 = bid * (RW * 64) + (wave / CW) * 64;
    const int rt0 = row0 >> 4;

    f32x4 acc[4][4];
#pragma unroll
    for (int rs = 0; rs < 4; rs++)
#pragma unroll
        for (int t = 0; t < 4; t++) acc[rs][t] = (f32x4){0.f, 0.f, 0.f, 0.f};

    const unsigned short* aph[4];
    const unsigned short* apl[4];
#pragma unroll
    for (int rs = 0; rs < 4; rs++) {
        size_t off = (((size_t)(rt0 + rs) * NCH) * 64 + lane) * 8;
        aph[rs] = Ah + off;
        if (ALO) apl[rs] = Al + off;
    }
    const unsigned short* bh = Wf_hi + ((size_t)(col0 >> 4) * NCH * 64 + lane) * 8;
    const unsigned short* bl = Wf_lo + ((size_t)(col0 >> 4) * NCH * 64 + lane) * 8;

#pragma unroll
    for (int ch = 0; ch < NCH; ch++) {
        BU a_h[4], a_l[4], b_h[4], b_l[4];
#pragma unroll
        for (int rs = 0; rs < 4; rs++) {
            a_h[rs].u = *(const us8*)(aph[rs] + ch * 512);
            if (ALO) a_l[rs].u = *(const us8*)(apl[rs] + ch * 512);
        }
#pragma unroll
        for (int t = 0; t < 4; t++) {
            b_h[t].u = *(const us8*)(bh + (size_t)(t * NCH + ch) * 512);
            b_l[t].u = *(const us8*)(bl + (size_t)(t * NCH + ch) * 512);
        }
#pragma unroll
        for (int t = 0; t < 4; t++) {
#pragma unroll
            for (int rs = 0; rs < 4; rs++) {
                acc[rs][t] = __builtin_amdgcn_mfma_f32_16x16x32_bf16(a_h[rs].b, b_h[t].b, acc[rs][t], 0, 0, 0);
                acc[rs][t] = __builtin_amdgcn_mfma_f32_16x16x32_bf16(a_h[rs].b, b_l[t].b, acc[rs][t], 0, 0, 0);
                if (ALO)
                    acc[rs][t] = __builtin_amdgcn_mfma_f32_16x16x32_bf16(a_l[rs].b, b_h[t].b, acc[rs][t], 0, 0, 0);
            }
        }
    }

    float sv[4], dv[4];
#pragma unroll
    for (int t = 0; t < 4; t++) {
        sv[t] = a_src[col0 + t * 16 + l16];
        dv[t] = a_dst[col0 + t * 16 + l16];
    }
#pragma unroll
    for (int rs = 0; rs < 4; rs++) {
        const int orow0 = row0 + rs * 16 + quad * 4;
#pragma unroll
        for (int i = 0; i < 4; i++) {
            int r = orow0 + i;
            bool ok = (r < n_rows);
            float ps = 0.f, pd = 0.f;
#pragma unroll
            for (int t = 0; t < 4; t++) {
                float v = acc[rs][t][i];
                ps += v * sv[t];
                pd += v * dv[t];
                if (ok) Hout[(size_t)r * M + col0 + t * 16 + l16] = f2bf(v);
            }
            ps += __shfl_xor(ps, 1);  pd += __shfl_xor(pd, 1);
            ps += __shfl_xor(ps, 2);  pd += __shfl_xor(pd, 2);
            ps += __shfl_xor(ps, 4);  pd += __shfl_xor(pd, 4);
            ps += __shfl_xor(ps, 8);  pd += __shfl_xor(pd, 8);
            if (l16 == 0 && ok) {
                als[r * H_ + head] = ps;
                ald[r * H_ + head] = pd;
            }
        }
    }
}

#define NT_G1 ((N_NODES + 63) / 64)      // 782 gemm1 tiles
#define NT_SC ((E2_EDGES + 255) / 256)   // 2149 scatter tiles

// ===== merged layer-1 GEMM + CSR scatter (independent work, one launch): ====
// removes one kernel boundary and hides scatter's ~7us under the GEMM.
__global__ __launch_bounds__(256) void gemm1_scatter_kernel(
    const unsigned short* __restrict__ Ah, const unsigned short* __restrict__ Al,
    const unsigned short* __restrict__ Wf_hi, const unsigned short* __restrict__ Wf_lo,
    const float* __restrict__ a_src, const float* __restrict__ a_dst,
    unsigned short* __restrict__ Hout, float* __restrict__ als,
    float* __restrict__ ald,
    const int* __restrict__ ei, int* __restrict__ deg,
    unsigned short* __restrict__ slots) {
    if (blockIdx.x < NT_G1)
        gemm_tile<F_IN, HC, true>(blockIdx.x, Ah, Al, Wf_hi, Wf_lo, a_src, a_dst,
                                  Hout, als, ald, N_NODES);
    else
        scatter_tile(blockIdx.x - NT_G1, ei, deg, slots);
}

template<int K, int M, bool ALO>
__global__ __launch_bounds__(256) void mfma_lin_fused_kernel(
    const unsigned short* __restrict__ Ah, const unsigned short* __restrict__ Al,
    const unsigned short* __restrict__ Wf_hi, const unsigned short* __restrict__ Wf_lo,
    const float* __restrict__ a_src, const float* __restrict__ a_dst,
    unsigned short* __restrict__ Hout, float* __restrict__ als,
    float* __restrict__ ald, int n_rows) {
    gemm_tile<K, M, ALO>(blockIdx.x, Ah, Al, Wf_hi, Wf_lo, a_src, a_dst, Hout, als, ald, n_rows);
}

// ===== agg (layers 1,2): bucketed ushort slots, v8 batch structure =====
// (at its ~3.3 TB/s / ~88K-lines-per-us gather ceiling; v5/v7/v8 all ~50us)
__global__ __launch_bounds__(256, 4) void gat_agg_v3_kernel(
    const unsigned short* __restrict__ slots, const int* __restrict__ deg,
    const unsigned short* __restrict__ h,
    const float* __restrict__ als, const float* __restrict__ ald,
    const float* __restrict__ bias, unsigned short* __restrict__ outh) {
    constexpr int LP = 264;            // LDS row stride (shorts), 16B-aligned
    __shared__ unsigned short smh[16 * LP];
    const int tid = threadIdx.x;
    const int wave = tid >> 6, lane = tid & 63;
    const int cl = lane & 31, half = lane >> 5;
    const int head = cl >> 3;          // 8 lanes per head (8 ch each)
    const int rt = blockIdx.x;         // row tile: nodes rt*16 .. rt*16+15

    float bv[8];
#pragma unroll
    for (int i = 0; i < 8; i++) bv[i] = bias[cl * 8 + i];

    const int nb = rt * 16 + wave * 4;
    int lenv[4];
    float adv[4];
#pragma unroll
    for (int nn = 0; nn < 4; nn++) {
        lenv[nn] = min(deg[nb + nn], SLOT_CAP);
        adv[nn] = ald[((nb + nn) << 2) + head];
    }
    const unsigned short* hp = h + cl * 8;

    for (int nn = 0; nn < 4; nn++) {
        const int len = lenv[nn];
        const int lm = len - 1;          // len >= 1 (self loop)
        const int base = (nb + nn) << 6; // slot base
        const float ad = adv[nn];
        float z = 0.f;
        float a[8];
#pragma unroll
        for (int i = 0; i < 8; i++) a[i] = 0.f;
        for (int k = 0; k < len; k += 16) {
            int ss[8];
#pragma unroll
            for (int j = 0; j < 8; j++) {
                int ii = min(k + 2 * j + half, lm);
                ss[j] = (int)slots[base + ii];
            }
            __builtin_amdgcn_sched_barrier(0);
            us8 hv[8];
            float alv[8];
#pragma unroll
            for (int j = 0; j < 8; j++) {
                hv[j] = *(const us8*)(hp + ((size_t)ss[j] << 8));
                alv[j] = als[(ss[j] << 2) + head];
            }
            __builtin_amdgcn_sched_barrier(0);
            float p[8];
#pragma unroll
            for (int j = 0; j < 8; j++) {
                float x = alv[j] + ad;
                x = (x > 0.f) ? x : 0.2f * x;
                int e = k + 2 * j + half;
                p[j] = (e < len) ? __expf(x) : 0.f;
                z += p[j];
            }
#pragma unroll
            for (int j = 0; j < 8; j++)
#pragma unroll
                for (int i = 0; i < 8; i++)
                    a[i] += p[j] * bf2f(hv[j][i]);
        }
        z += __shfl_xor(z, 32);
#pragma unroll
        for (int i = 0; i < 8; i++) a[i] += __shfl_xor(a[i], 32);
        if (half == 0) {
            float inv = 1.f / (z + 1e-16f);
            us8 vh;
#pragma unroll
            for (int i = 0; i < 8; i++) {
                float v = fmaxf(a[i] * inv + bv[i], 0.f);   // relu (layers 1,2)
                vh[i] = f2bf(v);
            }
            int nl = wave * 4 + nn;
            *(us8*)(smh + nl * LP + cl * 8) = vh;
        }
    }
    __syncthreads();
#pragma unroll
    for (int f = tid; f < 512; f += 256) {
        int chunk = f >> 6, ln2 = f & 63;
        int quad = ln2 >> 4, l16 = ln2 & 15;
        us8 vh = *(const us8*)(smh + l16 * LP + chunk * 32 + quad * 8);
        size_t dst = (((size_t)rt * 8 + chunk) * 64 + ln2) * 8;
        *(us8*)(outh + dst) = vh;
    }
}

// ===== layer-3 agg: one wave/node, per-node coalesced fp32 writes to bufO3.
// Grid 12500 blocks = gather-rate saturated (round-10's 1000-block fusion
// collapsed the rate 4.6x -- grid must stay above saturation).
__global__ __launch_bounds__(256) void gat_agg_h1_kernel(
    const unsigned short* __restrict__ slots, const int* __restrict__ deg,
    const unsigned short* __restrict__ h,
    const float* __restrict__ als, const float* __restrict__ ald,
    const float* __restrict__ bias, float* __restrict__ out, int n) {
    const int wave = threadIdx.x >> 6, lane = threadIdx.x & 63;
    const int eg = lane >> 3, cg = lane & 7;   // edge slot, channel group
    const int node = (blockIdx.x << 2) + wave;
    if (node >= n) return;
    const int base = node << 6;
    const int len = min(deg[node], SLOT_CAP);
    const float ad = ald[node];
    float z = 0.f;
    float a[8];
#pragma unroll
    for (int i = 0; i < 8; i++) a[i] = 0.f;
    const unsigned short* hp = h + cg * 8;
    for (int k = 0; k < len; k += 8) {
        int e = k + eg;
        int s0 = (int)slots[base + min(e, len - 1)];
        us8 hv = *(const us8*)(hp + ((size_t)s0 << 6));
        float x = als[s0] + ad;
        x = (x > 0.f) ? x : 0.2f * x;
        float p = (e < len) ? __expf(x) : 0.f;
        z += p;
#pragma unroll
        for (int i = 0; i < 8; i++) a[i] += p * bf2f(hv[i]);
    }
#pragma unroll
    for (int off = 8; off <= 32; off <<= 1) {
        z += __shfl_xor(z, off);
#pragma unroll
        for (int i = 0; i < 8; i++) a[i] += __shfl_xor(a[i], off);
    }
    if (eg == 0) {
        float inv = 1.f / (z + 1e-16f);
        float* op = out + ((size_t)node << 6) + cg * 8;
        float4 o0, o1;
        o0.x = a[0] * inv + bias[cg * 8 + 0];
        o0.y = a[1] * inv + bias[cg * 8 + 1];
        o0.z = a[2] * inv + bias[cg * 8 + 2];
        o0.w = a[3] * inv + bias[cg * 8 + 3];
        o1.x = a[4] * inv + bias[cg * 8 + 4];
        o1.y = a[5] * inv + bias[cg * 8 + 5];
        o1.z = a[6] * inv + bias[cg * 8 + 6];
        o1.w = a[7] * inv + bias[cg * 8 + 7];
        *(float4*)op = o0;
        *(float4*)(op + 4) = o1;
    }
}

// ===== fused head: mean-pool + MLP1(relu) + MLP2 + LayerNorm =====
__global__ __launch_bounds__(256) void head_fused_kernel(
    const float* __restrict__ h3, const int* __restrict__ batch,
    const float* __restrict__ Wm1, const float* __restrict__ bm1,
    const float* __restrict__ Wm2, const float* __restrict__ bm2,
    const float* __restrict__ g2, const float* __restrict__ be2,
    float* __restrict__ out) {
    const int b = blockIdx.x;
    const int tid = threadIdx.x;
    // node range of graph b (batch is sorted) -- redundant binary search
    int lo = 0, hi = N_NODES;
    while (lo < hi) { int mid = (lo + hi) >> 1; if (batch[mid] < b) lo = mid + 1; else hi = mid; }
    const int start = lo;
    hi = N_NODES;
    while (lo < hi) { int mid = (lo + hi) >> 1; if (batch[mid] < b + 1) lo = mid + 1; else hi = mid; }
    const int end = lo;

    __shared__ float pr[4][CH];
    __shared__ float xg[CH];
    __shared__ float yr[NHID];
    const int j = tid & 63, g = tid >> 6;
    // mean pool: 4 row-groups x 64 channels
    float s = 0.f;
    for (int n = start + g; n < end; n += 4) s += h3[(size_t)n * CH + j];
    pr[g][j] = s;
    __syncthreads();
    if (tid < CH) {
        float t = pr[0][tid] + pr[1][tid] + pr[2][tid] + pr[3][tid];
        xg[tid] = t / fmaxf((float)(end - start), 1.f);
    }
    __syncthreads();
    // MLP1: y1 = relu(xg @ Wm1 + bm1)
    float acc1 = bm1[tid];
#pragma unroll 8
    for (int k = 0; k < CH; k++) acc1 += xg[k] * Wm1[(size_t)k * NHID + tid];
    yr[tid] = fmaxf(acc1, 0.f);
    __syncthreads();
    // MLP2: y2 = y1 @ Wm2 + bm2
    float acc = bm2[tid];
#pragma unroll 8
    for (int k = 0; k < NHID; k++) acc += yr[k] * Wm2[(size_t)k * NOUT + tid];
    // LayerNorm over 256
    float ss = acc, s2 = acc * acc;
    for (int o = 32; o > 0; o >>= 1) {
        ss += __shfl_down(ss, o);
        s2 += __shfl_down(s2, o);
    }
    __shared__ float red[8];
    __shared__ float mv[2];
    int wave = tid >> 6, lane = tid & 63;
    if (lane == 0) { red[wave] = ss; red[4 + wave] = s2; }
    __syncthreads();
    if (tid == 0) {
        float ts = red[0] + red[1] + red[2] + red[3];
        float ts2 = red[4] + red[5] + red[6] + red[7];
        float mu = ts / (float)NOUT;
        float var = ts2 / (float)NOUT - mu * mu;
        mv[0] = mu;
        mv[1] = rsqrtf(var + 1e-5f);
    }
    __syncthreads();
    out[(size_t)b * NOUT + tid] = (acc - mv[0]) * mv[1] * g2[tid] + be2[tid];
}

extern "C" void kernel_launch(void* const* d_in, const int* in_sizes, int n_in,
                              void* d_out, int out_size, void* d_ws, size_t ws_size,
                              hipStream_t stream) {
    const float* x      = (const float*)d_in[0];
    const int*   ei     = (const int*)d_in[1];
    const int*   batch  = (const int*)d_in[2];
    const float* W1     = (const float*)d_in[3];
    const float* as1    = (const float*)d_in[4];
    const float* ad1    = (const float*)d_in[5];
    const float* b1     = (const float*)d_in[6];
    const float* W2     = (const float*)d_in[7];
    const float* as2    = (const float*)d_in[8];
    const float* ad2    = (const float*)d_in[9];
    const float* b2     = (const float*)d_in[10];
    const float* W3     = (const float*)d_in[11];
    const float* as3    = (const float*)d_in[12];
    const float* ad3    = (const float*)d_in[13];
    const float* b3     = (const float*)d_in[14];
    const float* Wm1    = (const float*)d_in[15];
    const float* bm1    = (const float*)d_in[16];
    const float* Wm2    = (const float*)d_in[17];
    const float* bm2    = (const float*)d_in[18];
    const float* g2     = (const float*)d_in[19];
    const float* be2    = (const float*)d_in[20];
    float* out = (float*)d_out;

    // workspace layout (~66.6MB; bufO3 overlays aggh -- aggh dead after gemm3
    // reads it, bufO3 written by agg_h1 strictly after under stream order)
    unsigned short* bufH = (unsigned short*)d_ws;                  // N*HC bf16
    unsigned short* aggh = bufH + (size_t)N_NODES * HC;            // N_PAD*HC frag-major
    float* bufO3 = (float*)aggh;                                   // N*CH fp32 (overlay)
    unsigned short* xh   = aggh + (size_t)N_PAD * HC;              // N_PAD*F_IN
    unsigned short* xl   = xh + (size_t)N_PAD * F_IN;              // N_PAD*F_IN
    unsigned short* slots = xl + (size_t)N_PAD * F_IN;             // N*SLOT_CAP (dedicated)
    float* als   = (float*)(slots + (size_t)N_NODES * SLOT_CAP);   // N*HEADS
    float* ald   = als + (size_t)N_NODES * HEADS;                  // N*HEADS
    int* deg     = (int*)(ald + (size_t)N_NODES * HEADS);          // N
    unsigned short* wt1h = (unsigned short*)(deg + N_NODES);       // 256*32
    unsigned short* wt1l = wt1h + 256 * 32;
    unsigned short* wt2h = wt1l + 256 * 32;                        // 256*256
    unsigned short* wt2l = wt2h + 256 * 256;
    unsigned short* wt3h = wt2l + 256 * 256;                       // 64*256
    unsigned short* wt3l = wt3h + 64 * 256;

    const int BLK = 256;

    // ===================== fused prep (deg zero, x split, W conv) ============
    prep_kernel<<<cdiv(PREP_T4, BLK), BLK, 0, stream>>>(
        x, xh, xl, W1, wt1h, wt1l, W2, wt2h, wt2l, W3, wt3h, wt3l, deg);

    // ===================== Layer-1 GEMM + CSR scatter (merged launch) ========
    gemm1_scatter_kernel<<<NT_G1 + NT_SC, 256, 0, stream>>>(
        xh, xl, wt1h, wt1l, as1, ad1, bufH, als, ald, ei, deg, slots);

    // ===================== Layer 1 aggregation =====================
    gat_agg_v3_kernel<<<N_NODES / 16, 256, 0, stream>>>(
        slots, deg, bufH, als, ald, b1, aggh);

    // ===================== Layer 2 (H*C -> H*C) =====================
    mfma_lin_fused_kernel<HC, HC, false><<<cdiv(N_NODES, 64), 256, 0, stream>>>(
        aggh, nullptr, wt2h, wt2l, as2, ad2, bufH, als, ald, N_NODES);
    gat_agg_v3_kernel<<<N_NODES / 16, 256, 0, stream>>>(
        slots, deg, bufH, als, ald, b2, aggh);

    // ===================== Layer 3 (H*C -> C, heads=1) =====================
    mfma_lin_fused_kernel<HC, CH, false><<<cdiv(N_NODES, 256), 256, 0, stream>>>(
        aggh, nullptr, wt3h, wt3l, as3, ad3, bufH, als, ald, N_NODES);
    gat_agg_h1_kernel<<<cdiv(N_NODES, 4), 256, 0, stream>>>(
        slots, deg, bufH, als, ald, b3, bufO3, N_NODES);

    // ===================== fused head: pool + MLP + LayerNorm ================
    head_fused_kernel<<<NB, 256, 0, stream>>>(
        bufO3, batch, Wm1, bm1, Wm2, bm2, g2, be2, out);
}